// Round 4
// baseline (232.203 us; speedup 1.0000x reference)
//
#include <hip/hip_runtime.h>
#include <math.h>

#define BATCH 8
#define CH    256
#define H     128
#define W     128
#define HW    (H * W)          // 16384
#define OH    65
#define OW    65
#define NPIX  (OH * OW)        // 4225
#define TPB   512
#define WAVES 8
#define CPW   (CH / WAVES)     // 32 channels per wave

// Fused kernel, occupancy-first. One block = one output row (oh) of one image,
// all 256 channels. Lane l owns input columns (2l, 2l+1) of the 3 clamped rows.
//   phase 1: stream this wave's 32 channels (3 float2/channel), accumulate
//            channel sum-of-squares. Nothing retained (keeps VGPR ~50).
//   reduce:  LDS tree -> strip norms -> 65 softmax weight sets.
//   phase 2: RE-LOAD the same 3 float2 per channel (same lane, same address ->
//            L1/L2 hit; L3 holds the strip regardless), pool via the S/T
//            shuffle decomposition, coalesced stores.
// __launch_bounds__(512, 6): VGPR cap 85 -> 3 blocks/CU -> all 520 blocks
// co-resident (520 <= 768): no tail, 24 waves/CU hide load + barrier latency.
__global__ __launch_bounds__(TPB, 6) void fused_kernel(const float* __restrict__ x,
                                                       float* __restrict__ out) {
    // b = bid & 7 pins each image to one XCD (dispatch round-robins bid % 8),
    // so adjacent-oh blocks (which share even input rows) land on the same L2.
    const int b    = blockIdx.x & 7;
    const int oh   = blockIdx.x >> 3;
    const int tid  = threadIdx.x;
    const int lane = tid & 63;
    const int wv   = tid >> 6;

    // clamped input rows for this output row (block-uniform)
    int  rowc[3];
    bool rv[3];
    #pragma unroll
    for (int r = 0; r < 3; ++r) {
        int ih = oh * 2 + r - 2;
        rv[r]   = (unsigned)ih < (unsigned)H;
        rowc[r] = ih < 0 ? 0 : (ih > H - 1 ? H - 1 : ih);
    }

    __shared__ float part[WAVES][3][W];  // 12 KB  per-wave per-row partial SSQ
    __shared__ float nrm[3][W];          // 1.5 KB strip channel-norms
    __shared__ float wls[OH][9];         // 2.3 KB softmax weights (stride 9 = odd)

    const float2* xw2 = (const float2*)x + (size_t)(b * CH + wv * CPW) * (HW / 2);
    const int base0 = rowc[0] * (W / 2) + lane;
    const int base1 = rowc[1] * (W / 2) + lane;
    const int base2 = rowc[2] * (W / 2) + lane;

    // ---- phase 1: sum of squares over this wave's 32 channels ----
    float2 a0 = {0.f, 0.f}, a1 = {0.f, 0.f}, a2 = {0.f, 0.f};
    #pragma unroll 8
    for (int c = 0; c < CPW; ++c) {
        const size_t cb = (size_t)c * (HW / 2);
        float2 v0 = xw2[cb + base0];
        float2 v1 = xw2[cb + base1];
        float2 v2 = xw2[cb + base2];
        a0.x += v0.x * v0.x; a0.y += v0.y * v0.y;
        a1.x += v1.x * v1.x; a1.y += v1.y * v1.y;
        a2.x += v2.x * v2.x; a2.y += v2.y * v2.y;
    }
    *(float2*)&part[wv][0][2 * lane] = a0;
    *(float2*)&part[wv][1][2 * lane] = a1;
    *(float2*)&part[wv][2][2 * lane] = a2;
    __syncthreads();

    // ---- cross-wave reduce -> norms (384 threads, stride-1 -> conflict-free) ----
    if (tid < 3 * W) {
        int r = tid >> 7, col = tid & (W - 1);
        float s = 0.f;
        #pragma unroll
        for (int w = 0; w < WAVES; ++w) s += part[w][r][col];
        nrm[r][col] = sqrtf(s);
    }
    __syncthreads();

    // ---- softmax weights for the 65 output columns (verified math) ----
    if (tid < OH) {
        const int ow  = tid;
        const int iw0 = ow * 2 - 2;
        float nv[9];
        bool  val[9];
        float m = 0.0f;
        #pragma unroll
        for (int kh = 0; kh < 3; ++kh) {
            bool vh = rv[kh];
            #pragma unroll
            for (int kw = 0; kw < 3; ++kw) {
                int iw = iw0 + kw;
                int k  = kh * 3 + kw;
                bool v = vh && ((unsigned)iw < (unsigned)W);
                val[k] = v;
                nv[k]  = v ? nrm[kh][iw] : 0.0f;
                m = fmaxf(m, nv[k]);
            }
        }
        float denom = 0.0f, wt[9];
        #pragma unroll
        for (int k = 0; k < 9; ++k) {
            float e = __expf(nv[k] - m);
            denom += e;
            wt[k] = val[k] ? e : 0.0f;
        }
        float inv = 1.0f / denom;
        #pragma unroll
        for (int k = 0; k < 9; ++k) wls[ow][k] = wt[k] * inv;
    }
    __syncthreads();

    // ---- phase 2: pool; reload strip (L1/L2-hot: same lane, same addresses) ----
    // lane l: T = own-ow (l) kw=2 terms on x[2l]; S = ow=l+1 kw=0,1 terms on
    // x[2l],x[2l+1]; out[ow] = T_ow + S_{ow-1} via one __shfl_up.
    // out[64] = S_63 (its kw=2 weight is OOB-zero).
    const float wA0 = wls[lane][2], wA1 = wls[lane][5], wA2 = wls[lane][8];
    const float wB0 = wls[lane + 1][0], wC0 = wls[lane + 1][1];
    const float wB1 = wls[lane + 1][3], wC1 = wls[lane + 1][4];
    const float wB2 = wls[lane + 1][6], wC2 = wls[lane + 1][7];

    float* ob = out + (size_t)(b * CH + wv * CPW) * NPIX + (size_t)oh * OW;
    #pragma unroll 4
    for (int c = 0; c < CPW; ++c) {
        const size_t cb = (size_t)c * (HW / 2);
        float2 v0 = xw2[cb + base0];
        float2 v1 = xw2[cb + base1];
        float2 v2 = xw2[cb + base2];
        float S = wB0 * v0.x + wC0 * v0.y
                + wB1 * v1.x + wC1 * v1.y
                + wB2 * v2.x + wC2 * v2.y;            // -> out[lane+1]
        float T = wA0 * v0.x + wA1 * v1.x + wA2 * v2.x;  // -> out[lane]
        float Sp = __shfl_up(S, 1);
        float res = (lane == 0) ? T : T + Sp;
        ob[(size_t)c * NPIX + lane] = res;               // coalesced 64-float run
        if (lane == 63) ob[(size_t)c * NPIX + 64] = S;   // ow=64
    }
}

extern "C" void kernel_launch(void* const* d_in, const int* in_sizes, int n_in,
                              void* d_out, int out_size, void* d_ws, size_t ws_size,
                              hipStream_t stream) {
    const float* x = (const float*)d_in[0];
    float* out = (float*)d_out;
    (void)d_ws; (void)ws_size;
    // 8 images * 65 output rows = 520 blocks, all co-resident at 3 blocks/CU
    fused_kernel<<<BATCH * OH, TPB, 0, stream>>>(x, out);
}